// Round 12
// baseline (236.606 us; speedup 1.0000x reference)
//
#include <hip/hip_runtime.h>
#include <math.h>

#define NH 12
#define DM 768
#define HD 64
#define BB 4
#define TT 2048
#define MTOT (BB*TT)   // 8192

// 1/sqrt(64) * log2(e) — folded into Q at the QKV-GEMM epilogue
#define QSCALE 0.1803368801111204f

#define PACKX_BLOCKS 6144   // MTOT*DM/4/256

typedef short bf16x8 __attribute__((ext_vector_type(8)));
typedef short bf16x4 __attribute__((ext_vector_type(4)));
typedef float f32x4 __attribute__((ext_vector_type(4)));
typedef int   i32x4 __attribute__((ext_vector_type(4)));
typedef int   i32x2 __attribute__((ext_vector_type(2)));
typedef unsigned int u32;

#define GLDS(g, l) __builtin_amdgcn_global_load_lds((const __attribute__((address_space(1))) u32*)(g), (__attribute__((address_space(3))) u32*)(l), 16, 0, 0)

__device__ __forceinline__ unsigned short f2bf(float f) {
    unsigned u = __float_as_uint(f);
    u += 0x7fff + ((u >> 16) & 1);   // RNE
    return (unsigned short)(u >> 16);
}

// ---------------- merged pack kernel ----------------
// blocks [0,6144): x -> bf16
// blocks [6144,6576): Wq/Wk/Wv transpose-pack
// blocks [6576,6720): Wo transpose-pack
// block  6720: gated output bias
__global__ void k_pack_all(const float* __restrict__ x, unsigned short* __restrict__ xb,
                           const float* __restrict__ Wq, const float* __restrict__ Wk,
                           const float* __restrict__ Wv, unsigned short* __restrict__ wqkv,
                           const float* __restrict__ Wo, const float* __restrict__ gate,
                           unsigned short* __restrict__ wob,
                           const float* __restrict__ bo, float* __restrict__ bias) {
    const int bid = blockIdx.x;
    if (bid < PACKX_BLOCKS) {
        int i = (bid * 256 + threadIdx.x) * 4;
        float4 v = *(const float4*)(x + i);
        ushort4 o = { f2bf(v.x), f2bf(v.y), f2bf(v.z), f2bf(v.w) };
        *(ushort4*)(xb + i) = o;
        return;
    }
    __shared__ unsigned short L[64][72];   // +8 pad
    if (bid < PACKX_BLOCKS + 432) {
        const int b2 = bid - PACKX_BLOCKS;
        const int q = b2 / 144, r = b2 % 144, h = r / 12, kt = r % 12;
        const float* W = (q == 0 ? Wq : (q == 1 ? Wk : Wv)) + (size_t)h * DM * HD + (size_t)kt * 64 * HD;
        #pragma unroll
        for (int it = 0; it < 4; it++) {
            int idx = it * 256 + threadIdx.x;
            int rr = idx >> 4, e4 = (idx & 15) * 4;      // rr = kd_local (coalesced float4 along e)
            float4 v = *(const float4*)&W[(size_t)rr * HD + e4];
            L[e4    ][rr] = f2bf(v.x);
            L[e4 + 1][rr] = f2bf(v.y);
            L[e4 + 2][rr] = f2bf(v.z);
            L[e4 + 3][rr] = f2bf(v.w);
        }
        __syncthreads();
        #pragma unroll
        for (int it = 0; it < 2; it++) {
            int idx = it * 256 + threadIdx.x;
            int e = idx >> 3, c8 = (idx & 7) * 8;
            *(bf16x8*)&wqkv[(size_t)(q * 768 + h * 64 + e) * DM + kt * 64 + c8] = *(const bf16x8*)&L[e][c8];
        }
        return;
    }
    const int b3 = bid - (PACKX_BLOCKS + 432);
    if (b3 == 144) {
        #pragma unroll
        for (int it = 0; it < 3; it++) {
            int d = it * 256 + threadIdx.x;
            float s = 0.f;
            #pragma unroll
            for (int h = 0; h < NH; h++) {
                float g = gate[h]; g = (g < 1e-6f) ? 0.f : g;
                s += g * bo[h * DM + d];
            }
            bias[d] = s;
        }
        return;
    }
    const int ht = b3 / 12, dt = b3 % 12;
    float g = gate[ht]; g = (g < 1e-6f) ? 0.f : g;
    const float* W = Wo + (size_t)ht * 64 * DM + dt * 64;
    #pragma unroll
    for (int it = 0; it < 4; it++) {
        int idx = it * 256 + threadIdx.x;
        int rr = idx >> 4, d4 = (idx & 15) * 4;      // rr = e_local (coalesced float4 along d)
        float4 v = *(const float4*)&W[(size_t)rr * DM + d4];
        L[d4    ][rr] = f2bf(g * v.x);
        L[d4 + 1][rr] = f2bf(g * v.y);
        L[d4 + 2][rr] = f2bf(g * v.z);
        L[d4 + 3][rr] = f2bf(g * v.w);
    }
    __syncthreads();
    #pragma unroll
    for (int it = 0; it < 2; it++) {
        int idx = it * 256 + threadIdx.x;
        int d = idx >> 3, c8 = (idx & 7) * 8;
        *(bf16x8*)&wob[(size_t)(dt * 64 + d) * DM + ht * 64 + c8] = *(const bf16x8*)&L[d][c8];
    }
}

// ---------------- GEMM: QKV projection (64x128 tile, balanced 2304 blocks = 9/CU) ----------------
// Was 128x128 -> 1152 blocks = 4.5/CU (half-integer imbalance on the largest kernel).
// Wave tile 32x64, acc[2][4]; same LDS swizzle algebra (verified via the R10 out-retile).
// Q/K regions use OPERAND-SWAPPED MFMA: mfma(bf, af) -> lane holds 4 consecutive e at
// fixed t -> ushort4 stores into [t][e]. V region unswapped -> 8B stores into Vt[e][t].
__global__ __launch_bounds__(256) void k_gemm_qkv(
    const unsigned short* __restrict__ A,
    const unsigned short* __restrict__ Bt,
    const float* __restrict__ bq, const float* __restrict__ bk, const float* __restrict__ bv,
    unsigned short* __restrict__ Q, unsigned short* __restrict__ Kg, unsigned short* __restrict__ Vt)
{
    __shared__ unsigned short As[2][2048];   // 64 rows x 32 k
    __shared__ unsigned short Bs[2][4096];   // 128 rows x 32 k
    // XCD-chunked swizzle: 2304 blocks % 8 == 0, chunk = 288.
    const int flat = blockIdx.y * 18 + blockIdx.x;
    const int swz  = (flat & 7) * 288 + (flat >> 3);
    const int m0 = (swz / 18) * 64, n0 = (swz % 18) * 128;
    const int tid = threadIdx.x, lane = tid & 63, w = tid >> 6;
    const int wr = (w >> 1) * 32, wc = (w & 1) * 64;
    const int lr = lane & 15, lq = lane >> 4;

    const int arow = tid >> 2;
    const int ag   = ((tid & 3) ^ (arow & 3)) * 8;
    const int ldsw = w * 512;
    const int kg = (lq ^ (lr & 3)) * 8;

    const int region = n0 / DM;          // 0=Q 1=K 2=V (block-uniform)
    const int b  = m0 >> 11;
    const int tb = m0 & 2047;            // t-base within the batch

    #define STAGE_G(k0_, buf_) do { \
        const unsigned short* a_ = A  + (size_t)(m0 + arow) * DM + (k0_) + ag; \
        const unsigned short* b_ = Bt + (size_t)(n0 + arow) * DM + (k0_) + ag; \
        GLDS(a_,             &As[buf_][ldsw]); \
        GLDS(b_,             &Bs[buf_][ldsw]); \
        GLDS(b_ + 64 * DM,   &Bs[buf_][2048 + ldsw]); \
    } while (0)

    f32x4 acc[2][4] = {};
    STAGE_G(0, 0);

    if (region == 2) {
        for (int it = 0; it < DM / 32; it++) {
            const int cur = it & 1;
            __syncthreads();
            if (it < DM / 32 - 1) STAGE_G((it + 1) * 32, cur ^ 1);
            bf16x8 af[2], bf[4];
            #pragma unroll
            for (int rt = 0; rt < 2; rt++) af[rt] = *(const bf16x8*)&As[cur][(wr + rt*16 + lr) * 32 + kg];
            #pragma unroll
            for (int ct = 0; ct < 4; ct++) bf[ct] = *(const bf16x8*)&Bs[cur][(wc + ct*16 + lr) * 32 + kg];
            #pragma unroll
            for (int rt = 0; rt < 2; rt++)
                #pragma unroll
                for (int ct = 0; ct < 4; ct++)
                    acc[rt][ct] = __builtin_amdgcn_mfma_f32_16x16x32_bf16(af[rt], bf[ct], acc[rt][ct], 0, 0, 0);
        }
        // V epilogue: lane holds 4 consecutive t at fixed e -> 8B stores into Vt[e][t]
        #pragma unroll
        for (int rt = 0; rt < 2; rt++)
          #pragma unroll
          for (int ct = 0; ct < 4; ct++) {
            int n = n0 + wc + ct*16 + lr, r = n - 2*DM;
            int h = r >> 6, e = r & 63;
            int t0 = tb + wr + rt*16 + lq*4;
            float bias = bv[r];
            ushort4 o;
            o.x = f2bf(acc[rt][ct][0] + bias);
            o.y = f2bf(acc[rt][ct][1] + bias);
            o.z = f2bf(acc[rt][ct][2] + bias);
            o.w = f2bf(acc[rt][ct][3] + bias);
            *(ushort4*)&Vt[((size_t)(b*NH + h)*HD + e)*TT + t0] = o;
          }
    } else {
        for (int it = 0; it < DM / 32; it++) {
            const int cur = it & 1;
            __syncthreads();
            if (it < DM / 32 - 1) STAGE_G((it + 1) * 32, cur ^ 1);
            bf16x8 af[2], bf[4];
            #pragma unroll
            for (int rt = 0; rt < 2; rt++) af[rt] = *(const bf16x8*)&As[cur][(wr + rt*16 + lr) * 32 + kg];
            #pragma unroll
            for (int ct = 0; ct < 4; ct++) bf[ct] = *(const bf16x8*)&Bs[cur][(wc + ct*16 + lr) * 32 + kg];
            #pragma unroll
            for (int rt = 0; rt < 2; rt++)
                #pragma unroll
                for (int ct = 0; ct < 4; ct++)
                    acc[rt][ct] = __builtin_amdgcn_mfma_f32_16x16x32_bf16(bf[ct], af[rt], acc[rt][ct], 0, 0, 0);
        }
        // Swapped epilogue: D row (lq*4+i) = e within bf[ct] block; D col (lr) = t within af[rt]
        const float* bias_p = (region == 0) ? bq : bk;
        const float  scale  = (region == 0) ? QSCALE : 1.0f;
        unsigned short* dst = (region == 0) ? Q : Kg;
        #pragma unroll
        for (int ct = 0; ct < 4; ct++) {
            int r0 = n0 + wc + ct*16 + lq*4 - region*DM;
            int h = r0 >> 6, e = r0 & 63;
            float4 b4 = *(const float4*)&bias_p[r0];
            unsigned short* drow = dst + (size_t)(b*NH + h)*TT*HD + e;
            #pragma unroll
            for (int rt = 0; rt < 2; rt++) {
                int t = tb + wr + rt*16 + lr;
                ushort4 o;
                o.x = f2bf((acc[rt][ct][0] + b4.x) * scale);
                o.y = f2bf((acc[rt][ct][1] + b4.y) * scale);
                o.z = f2bf((acc[rt][ct][2] + b4.z) * scale);
                o.w = f2bf((acc[rt][ct][3] + b4.w) * scale);
                *(ushort4*)&drow[(size_t)t * HD] = o;
            }
        }
    }
    #undef STAGE_G
}

// ---------------- Flash attention v9: permlane P-redistribution (zero-LDS P) ----------------
// VERIFIED 65.0us, bank-conflict 0. K loaded with row-permutation sigma; x32 B-fragment
// via 2x v_permlane32_swap per pair set. v6/v8 lesson: MFMA operands MUST feed from LDS.
__global__ __launch_bounds__(256, 3) void k_flash(
    const unsigned short* __restrict__ Q, const unsigned short* __restrict__ Kg,
    const unsigned short* __restrict__ Vt, unsigned short* __restrict__ A2)
{
    __shared__ unsigned short Ks[2][4096];   // [buf][krow*64 + d-grp swizzled]
    __shared__ unsigned short Vs[2][4096];   // [buf][e*64 + t-grp swizzled]
    // XCD-chunked swizzle: 768 blocks % 8 == 0, chunk = 96 = 6 heads x 16 q-tiles.
    const int flat = blockIdx.y * (BB*NH) + blockIdx.x;
    const int swz  = (flat & 7) * 96 + (flat >> 3);
    const int bh = swz >> 4, qt = swz & 15;
    const int b = bh / NH, h = bh % NH;
    const int tid = threadIdx.x, lane = tid & 63, w = tid >> 6;
    const int col = lane & 15, quad = lane >> 4;
    const size_t qk_base = (size_t)bh * TT * HD;
    const size_t vt_base = (size_t)bh * HD * TT;
    const int tq0 = qt * 128 + w * 32;

    const int srow  = tid >> 3;
    const int sperm = (tid & 7) ^ (srow & 7);
    const int koff0 = srow * HD + sperm * 8;
    const int voff0 = srow * TT + sperm * 8;
    const int lds0  = w * 512;

    const unsigned short* ksrc = Kg + qk_base;
    const unsigned short* vsrc = Vt + vt_base;

    const int c7 = col & 7;
    // sigma-permuted K-row read: row = scol, XOR-swizzle keyed by scol&7
    const int scol = ((col >> 2) & 1) * 8 + ((col >> 3) & 1) * 4 + (col & 3);
    const int sc7  = scol & 7;
    const int ra0 = scol * 64 + (((    quad) ^ sc7) * 8);
    const int ra1 = scol * 64 + (((4 + quad) ^ sc7) * 8);

    bf16x8 aq[2][2];
    #pragma unroll
    for (int rt = 0; rt < 2; rt++)
        #pragma unroll
        for (int ks = 0; ks < 2; ks++)
            aq[rt][ks] = *(const bf16x8*)&Q[qk_base + (size_t)(tq0 + rt*16 + col) * HD + ks*32 + quad*8];

    const bf16x8 ones8 = { (short)0x3F80, (short)0x3F80, (short)0x3F80, (short)0x3F80,
                           (short)0x3F80, (short)0x3F80, (short)0x3F80, (short)0x3F80 };

    f32x4 co[4][2] = {};
    f32x4 lacc[2] = {};

    #define STAGE(kt_, buf_) do { \
        const unsigned short* kb_ = ksrc + (size_t)(kt_) * 64 * HD; \
        const unsigned short* vb_ = vsrc + (kt_) * 64; \
        GLDS(kb_ + koff0,           &Ks[buf_][lds0]); \
        GLDS(kb_ + koff0 + 32*HD,   &Ks[buf_][lds0 + 2048]); \
        GLDS(vb_ + voff0,           &Vs[buf_][lds0]); \
        GLDS(vb_ + voff0 + 32*TT,   &Vs[buf_][lds0 + 2048]); \
    } while (0)

    STAGE(0, 0);

    for (int kt = 0; kt < TT/64; kt++) {
        const int cur = kt & 1;
        __syncthreads();
        if (kt < TT/64 - 1) STAGE(kt + 1, cur ^ 1);

        bf16x8 kf[4][2];
        #pragma unroll
        for (int ct = 0; ct < 4; ct++) {
            kf[ct][0] = *(const bf16x8*)&Ks[cur][ct*1024 + ra0];
            kf[ct][1] = *(const bf16x8*)&Ks[cur][ct*1024 + ra1];
        }

        f32x4 cs[4][2] = {};
        __builtin_amdgcn_s_setprio(1);
        #pragma unroll
        for (int ks = 0; ks < 2; ks++)
            #pragma unroll
            for (int ct = 0; ct < 4; ct++)
                #pragma unroll
                for (int rt = 0; rt < 2; rt++)
                    cs[ct][rt] = __builtin_amdgcn_mfma_f32_16x16x32_bf16(kf[ct][ks], aq[rt][ks], cs[ct][rt], 0, 0, 0);
        __builtin_amdgcn_s_setprio(0);

        // exp2 + pack to bf16 pairs: pk[rt][ct][m] = rows ct*16+sigma(quad*4+{2m,2m+1})
        int pk[2][4][2];
        #pragma unroll
        for (int rt = 0; rt < 2; rt++) {
            #pragma unroll
            for (int ct = 0; ct < 4; ct++) {
                float p0 = __builtin_amdgcn_exp2f(cs[ct][rt][0]);
                float p1 = __builtin_amdgcn_exp2f(cs[ct][rt][1]);
                float p2 = __builtin_amdgcn_exp2f(cs[ct][rt][2]);
                float p3 = __builtin_amdgcn_exp2f(cs[ct][rt][3]);
                pk[rt][ct][0] = (int)__builtin_amdgcn_perm(__float_as_uint(p1), __float_as_uint(p0), 0x07060302u);
                pk[rt][ct][1] = (int)__builtin_amdgcn_perm(__float_as_uint(p3), __float_as_uint(p2), 0x07060302u);
            }
        }

        // permlane32_swap redistribution -> x32 B-fragments (no LDS, no barrier)
        bf16x8 pf[2][2];
        #pragma unroll
        for (int rt = 0; rt < 2; rt++)
            #pragma unroll
            for (int k4 = 0; k4 < 2; k4++) {
                i32x2 s0 = __builtin_amdgcn_permlane32_swap(pk[rt][2*k4][0], pk[rt][2*k4+1][0], false, false);
                i32x2 s1 = __builtin_amdgcn_permlane32_swap(pk[rt][2*k4][1], pk[rt][2*k4+1][1], false, false);
                i32x4 pw; pw[0] = s0[0]; pw[1] = s1[0]; pw[2] = s0[1]; pw[3] = s1[1];
                pf[rt][k4] = __builtin_bit_cast(bf16x8, pw);
            }

        __builtin_amdgcn_s_setprio(1);
        #pragma unroll
        for (int rt = 0; rt < 2; rt++)
            #pragma unroll
            for (int k4 = 0; k4 < 2; k4++)
                lacc[rt] = __builtin_amdgcn_mfma_f32_16x16x32_bf16(ones8, pf[rt][k4], lacc[rt], 0, 0, 0);
        #pragma unroll
        for (int cv = 0; cv < 4; cv++) {
            #pragma unroll
            for (int k4 = 0; k4 < 2; k4++) {
                bf16x8 vf = *(const bf16x8*)&Vs[cur][cv*1024 + col*64 + ((k4*4 + quad) ^ c7)*8];
                #pragma unroll
                for (int rt = 0; rt < 2; rt++)
                    co[cv][rt] = __builtin_amdgcn_mfma_f32_16x16x32_bf16(vf, pf[rt][k4], co[cv][rt], 0, 0, 0);
            }
        }
        __builtin_amdgcn_s_setprio(0);
    }
    #undef STAGE

    #pragma unroll
    for (int rt = 0; rt < 2; rt++) {
        float inv = 1.0f / lacc[rt][0];   // ones-MFMA summed all k; all rows equal
        int t = tq0 + rt*16 + col;
        #pragma unroll
        for (int cv = 0; cv < 4; cv++) {
            ushort4 o;
            o.x = f2bf(co[cv][rt][0] * inv);
            o.y = f2bf(co[cv][rt][1] * inv);
            o.z = f2bf(co[cv][rt][2] * inv);
            o.w = f2bf(co[cv][rt][3] * inv);
            *(ushort4*)&A2[(size_t)(b*TT + t) * DM + h*HD + cv*16 + quad*4] = o;
        }
    }
}

// ---------------- GEMM: output projection (64x128 tile, balanced 768 blocks = 3/CU) ----------------
__global__ __launch_bounds__(256) void k_gemm_out(
    const unsigned short* __restrict__ A,
    const unsigned short* __restrict__ Bt,
    const float* __restrict__ bias,
    float* __restrict__ out)
{
    __shared__ unsigned short As[2][2048];   // 64 rows x 32 k
    __shared__ unsigned short Bs[2][4096];   // 128 rows x 32 k
    // XCD-chunked swizzle: 768 blocks % 8 == 0, chunk = 96.
    const int flat = blockIdx.y * 6 + blockIdx.x;
    const int swz  = (flat & 7) * 96 + (flat >> 3);
    const int m0 = (swz / 6) * 64, n0 = (swz % 6) * 128;
    const int tid = threadIdx.x, lane = tid & 63, w = tid >> 6;
    const int wr = (w >> 1) * 32, wc = (w & 1) * 64;
    const int lr = lane & 15, lq = lane >> 4;

    const int arow = tid >> 2;
    const int ag   = ((tid & 3) ^ (arow & 3)) * 8;
    const int ldsw = w * 512;
    const int kg = (lq ^ (lr & 3)) * 8;

    #define STAGE_G(k0_, buf_) do { \
        const unsigned short* a_ = A  + (size_t)(m0 + arow) * DM + (k0_) + ag; \
        const unsigned short* b_ = Bt + (size_t)(n0 + arow) * DM + (k0_) + ag; \
        GLDS(a_,             &As[buf_][ldsw]); \
        GLDS(b_,             &Bs[buf_][ldsw]); \
        GLDS(b_ + 64 * DM,   &Bs[buf_][2048 + ldsw]); \
    } while (0)

    f32x4 acc[2][4] = {};
    STAGE_G(0, 0);
    for (int it = 0; it < DM / 32; it++) {
        const int cur = it & 1;
        __syncthreads();
        if (it < DM / 32 - 1) STAGE_G((it + 1) * 32, cur ^ 1);
        bf16x8 af[2], bf[4];
        #pragma unroll
        for (int rt = 0; rt < 2; rt++) af[rt] = *(const bf16x8*)&As[cur][(wr + rt*16 + lr) * 32 + kg];
        #pragma unroll
        for (int ct = 0; ct < 4; ct++) bf[ct] = *(const bf16x8*)&Bs[cur][(wc + ct*16 + lr) * 32 + kg];
        #pragma unroll
        for (int rt = 0; rt < 2; rt++)
            #pragma unroll
            for (int ct = 0; ct < 4; ct++)
                acc[rt][ct] = __builtin_amdgcn_mfma_f32_16x16x32_bf16(bf[ct], af[rt], acc[rt][ct], 0, 0, 0);
    }
    #undef STAGE_G

    #pragma unroll
    for (int ct = 0; ct < 4; ct++) {
        int n = n0 + wc + ct*16 + lq*4;
        float4 b4 = *(const float4*)&bias[n];
        #pragma unroll
        for (int rt = 0; rt < 2; rt++) {
            int m = m0 + wr + rt*16 + lr;
            float4 o = { acc[rt][ct][0] + b4.x, acc[rt][ct][1] + b4.y,
                         acc[rt][ct][2] + b4.z, acc[rt][ct][3] + b4.w };
            *(float4*)&out[(size_t)m * DM + n] = o;
        }
    }
}

// ---------------- launcher ----------------
extern "C" void kernel_launch(void* const* d_in, const int* in_sizes, int n_in,
                              void* d_out, int out_size, void* d_ws, size_t ws_size,
                              hipStream_t stream) {
    const float* x    = (const float*)d_in[0];
    const float* Wq   = (const float*)d_in[1];
    const float* bq   = (const float*)d_in[2];
    const float* Wk   = (const float*)d_in[3];
    const float* bk   = (const float*)d_in[4];
    const float* Wv   = (const float*)d_in[5];
    const float* bv   = (const float*)d_in[6];
    const float* Wo   = (const float*)d_in[7];
    const float* bo   = (const float*)d_in[8];
    const float* gate = (const float*)d_in[9];
    float* out = (float*)d_out;

    char* p = (char*)d_ws;
    unsigned short* Xb   = (unsigned short*)p;  p += (size_t)MTOT*DM*2;
    unsigned short* Wqkv = (unsigned short*)p;  p += (size_t)3*DM*DM*2;
    unsigned short* Qb   = (unsigned short*)p;  p += (size_t)BB*NH*TT*HD*2;
    unsigned short* Kb   = (unsigned short*)p;  p += (size_t)BB*NH*TT*HD*2;
    unsigned short* Vtb  = (unsigned short*)p;  p += (size_t)BB*NH*TT*HD*2;
    unsigned short* A2   = (unsigned short*)p;  p += (size_t)MTOT*DM*2;
    unsigned short* Wob  = (unsigned short*)p;  p += (size_t)DM*DM*2;
    float*          bio  = (float*)p;           p += (size_t)DM*4;

    k_pack_all <<<PACKX_BLOCKS + 432 + 145, 256, 0, stream>>>(x, Xb, Wq, Wk, Wv, Wqkv, Wo, gate, Wob, bo, bio);
    k_gemm_qkv <<<dim3(18, MTOT/64), 256, 0, stream>>>(Xb, Wqkv, bq, bk, bv, Qb, Kb, Vtb);
    k_flash    <<<dim3(BB*NH, TT/128), 256, 0, stream>>>(Qb, Kb, Vtb, A2);
    k_gemm_out <<<dim3(DM/128, MTOT/64), 256, 0, stream>>>(A2, Wob, bio, out);
}

// Round 14
// 224.352 us; speedup vs baseline: 1.0546x; 1.0546x over previous
//
#include <hip/hip_runtime.h>
#include <math.h>

#define NH 12
#define DM 768
#define HD 64
#define BB 4
#define TT 2048
#define MTOT (BB*TT)   // 8192

// 1/sqrt(64) * log2(e) — folded into Q at the QKV-GEMM epilogue
#define QSCALE 0.1803368801111204f

#define PACKX_BLOCKS 6144   // MTOT*DM/4/256

typedef short bf16x8 __attribute__((ext_vector_type(8)));
typedef short bf16x4 __attribute__((ext_vector_type(4)));
typedef float f32x4 __attribute__((ext_vector_type(4)));
typedef int   i32x4 __attribute__((ext_vector_type(4)));
typedef int   i32x2 __attribute__((ext_vector_type(2)));
typedef unsigned int u32;

#define GLDS(g, l) __builtin_amdgcn_global_load_lds((const __attribute__((address_space(1))) u32*)(g), (__attribute__((address_space(3))) u32*)(l), 16, 0, 0)

__device__ __forceinline__ unsigned short f2bf(float f) {
    unsigned u = __float_as_uint(f);
    u += 0x7fff + ((u >> 16) & 1);   // RNE
    return (unsigned short)(u >> 16);
}

// ---------------- merged pack kernel ----------------
// blocks [0,6144): x -> bf16
// blocks [6144,6576): Wq/Wk/Wv transpose-pack
// blocks [6576,6720): Wo transpose-pack
// block  6720: gated output bias
__global__ void k_pack_all(const float* __restrict__ x, unsigned short* __restrict__ xb,
                           const float* __restrict__ Wq, const float* __restrict__ Wk,
                           const float* __restrict__ Wv, unsigned short* __restrict__ wqkv,
                           const float* __restrict__ Wo, const float* __restrict__ gate,
                           unsigned short* __restrict__ wob,
                           const float* __restrict__ bo, float* __restrict__ bias) {
    const int bid = blockIdx.x;
    if (bid < PACKX_BLOCKS) {
        int i = (bid * 256 + threadIdx.x) * 4;
        float4 v = *(const float4*)(x + i);
        ushort4 o = { f2bf(v.x), f2bf(v.y), f2bf(v.z), f2bf(v.w) };
        *(ushort4*)(xb + i) = o;
        return;
    }
    __shared__ unsigned short L[64][72];   // +8 pad
    if (bid < PACKX_BLOCKS + 432) {
        const int b2 = bid - PACKX_BLOCKS;
        const int q = b2 / 144, r = b2 % 144, h = r / 12, kt = r % 12;
        const float* W = (q == 0 ? Wq : (q == 1 ? Wk : Wv)) + (size_t)h * DM * HD + (size_t)kt * 64 * HD;
        #pragma unroll
        for (int it = 0; it < 4; it++) {
            int idx = it * 256 + threadIdx.x;
            int rr = idx >> 4, e4 = (idx & 15) * 4;      // rr = kd_local (coalesced float4 along e)
            float4 v = *(const float4*)&W[(size_t)rr * HD + e4];
            L[e4    ][rr] = f2bf(v.x);
            L[e4 + 1][rr] = f2bf(v.y);
            L[e4 + 2][rr] = f2bf(v.z);
            L[e4 + 3][rr] = f2bf(v.w);
        }
        __syncthreads();
        #pragma unroll
        for (int it = 0; it < 2; it++) {
            int idx = it * 256 + threadIdx.x;
            int e = idx >> 3, c8 = (idx & 7) * 8;
            *(bf16x8*)&wqkv[(size_t)(q * 768 + h * 64 + e) * DM + kt * 64 + c8] = *(const bf16x8*)&L[e][c8];
        }
        return;
    }
    const int b3 = bid - (PACKX_BLOCKS + 432);
    if (b3 == 144) {
        #pragma unroll
        for (int it = 0; it < 3; it++) {
            int d = it * 256 + threadIdx.x;
            float s = 0.f;
            #pragma unroll
            for (int h = 0; h < NH; h++) {
                float g = gate[h]; g = (g < 1e-6f) ? 0.f : g;
                s += g * bo[h * DM + d];
            }
            bias[d] = s;
        }
        return;
    }
    const int ht = b3 / 12, dt = b3 % 12;
    float g = gate[ht]; g = (g < 1e-6f) ? 0.f : g;
    const float* W = Wo + (size_t)ht * 64 * DM + dt * 64;
    #pragma unroll
    for (int it = 0; it < 4; it++) {
        int idx = it * 256 + threadIdx.x;
        int rr = idx >> 4, d4 = (idx & 15) * 4;      // rr = e_local (coalesced float4 along d)
        float4 v = *(const float4*)&W[(size_t)rr * DM + d4];
        L[d4    ][rr] = f2bf(g * v.x);
        L[d4 + 1][rr] = f2bf(g * v.y);
        L[d4 + 2][rr] = f2bf(g * v.z);
        L[d4 + 3][rr] = f2bf(g * v.w);
    }
    __syncthreads();
    #pragma unroll
    for (int it = 0; it < 2; it++) {
        int idx = it * 256 + threadIdx.x;
        int d = idx >> 3, c8 = (idx & 7) * 8;
        *(bf16x8*)&wob[(size_t)(dt * 64 + d) * DM + ht * 64 + c8] = *(const bf16x8*)&L[d][c8];
    }
}

// ---------------- GEMM: QKV projection (64x128 tile, BK=64: half the barriers) ----------------
// 2304 blocks = 9/CU balanced. BK 32->64: 12 K-steps instead of 24 -> half the
// s_barrier + vmcnt-drain convoy events (the profile showed all pipes <17% busy:
// barrier-convoy-bound). LDS 48KB dbuf (3 blocks/CU). Layout: 8 groups of 8 shorts
// per 64-k row; staged groups swizzled (tid&7)^(row&7); fragment group (ks*4+lq)^(lr&7).
// Q/K regions: OPERAND-SWAPPED MFMA -> ushort4 stores into [t][e]. V: Vt[e][t].
__global__ __launch_bounds__(256) void k_gemm_qkv(
    const unsigned short* __restrict__ A,
    const unsigned short* __restrict__ Bt,
    const float* __restrict__ bq, const float* __restrict__ bk, const float* __restrict__ bv,
    unsigned short* __restrict__ Q, unsigned short* __restrict__ Kg, unsigned short* __restrict__ Vt)
{
    __shared__ unsigned short As[2][4096];   // 64 rows x 64 k (8KB/buf)
    __shared__ unsigned short Bs[2][8192];   // 128 rows x 64 k (16KB/buf)
    // XCD-chunked swizzle: 2304 blocks % 8 == 0, chunk = 288.
    const int flat = blockIdx.y * 18 + blockIdx.x;
    const int swz  = (flat & 7) * 288 + (flat >> 3);
    const int m0 = (swz / 18) * 64, n0 = (swz % 18) * 128;
    const int tid = threadIdx.x, lane = tid & 63, w = tid >> 6;
    const int wr = (w >> 1) * 32, wc = (w & 1) * 64;
    const int lr = lane & 15, lq = lane >> 4;

    const int arow = tid >> 3;                    // 0..31 per 4KB GLDS call
    const int ag   = ((tid & 7) ^ (arow & 7)) * 8;
    const int ldsw = w * 512;
    const int l7 = lr & 7;
    const int kg0 = ((      lq) ^ l7) * 8;        // ks=0 fragment group
    const int kg1 = ((4 +   lq) ^ l7) * 8;        // ks=1 fragment group

    const int region = n0 / DM;          // 0=Q 1=K 2=V (block-uniform)
    const int b  = m0 >> 11;
    const int tb = m0 & 2047;            // t-base within the batch

    #define STAGE_G(k0_, buf_) do { \
        const unsigned short* a_ = A  + (size_t)(m0 + arow) * DM + (k0_) + ag; \
        const unsigned short* b_ = Bt + (size_t)(n0 + arow) * DM + (k0_) + ag; \
        GLDS(a_,             &As[buf_][ldsw]); \
        GLDS(a_ + 32 * DM,   &As[buf_][2048 + ldsw]); \
        GLDS(b_,             &Bs[buf_][ldsw]); \
        GLDS(b_ + 32 * DM,   &Bs[buf_][2048 + ldsw]); \
        GLDS(b_ + 64 * DM,   &Bs[buf_][4096 + ldsw]); \
        GLDS(b_ + 96 * DM,   &Bs[buf_][6144 + ldsw]); \
    } while (0)

    f32x4 acc[2][4] = {};
    STAGE_G(0, 0);

    if (region == 2) {
        for (int it = 0; it < DM / 64; it++) {
            const int cur = it & 1;
            __syncthreads();
            if (it < DM / 64 - 1) STAGE_G((it + 1) * 64, cur ^ 1);
            bf16x8 af[2][2], bf[4][2];
            #pragma unroll
            for (int rt = 0; rt < 2; rt++) {
                int ra = (wr + rt*16 + lr) * 64;
                af[rt][0] = *(const bf16x8*)&As[cur][ra + kg0];
                af[rt][1] = *(const bf16x8*)&As[cur][ra + kg1];
            }
            #pragma unroll
            for (int ct = 0; ct < 4; ct++) {
                int rb = (wc + ct*16 + lr) * 64;
                bf[ct][0] = *(const bf16x8*)&Bs[cur][rb + kg0];
                bf[ct][1] = *(const bf16x8*)&Bs[cur][rb + kg1];
            }
            #pragma unroll
            for (int ks = 0; ks < 2; ks++)
                #pragma unroll
                for (int rt = 0; rt < 2; rt++)
                    #pragma unroll
                    for (int ct = 0; ct < 4; ct++)
                        acc[rt][ct] = __builtin_amdgcn_mfma_f32_16x16x32_bf16(af[rt][ks], bf[ct][ks], acc[rt][ct], 0, 0, 0);
        }
        // V epilogue: lane holds 4 consecutive t at fixed e -> 8B stores into Vt[e][t]
        #pragma unroll
        for (int rt = 0; rt < 2; rt++)
          #pragma unroll
          for (int ct = 0; ct < 4; ct++) {
            int n = n0 + wc + ct*16 + lr, r = n - 2*DM;
            int h = r >> 6, e = r & 63;
            int t0 = tb + wr + rt*16 + lq*4;
            float bias = bv[r];
            ushort4 o;
            o.x = f2bf(acc[rt][ct][0] + bias);
            o.y = f2bf(acc[rt][ct][1] + bias);
            o.z = f2bf(acc[rt][ct][2] + bias);
            o.w = f2bf(acc[rt][ct][3] + bias);
            *(ushort4*)&Vt[((size_t)(b*NH + h)*HD + e)*TT + t0] = o;
          }
    } else {
        for (int it = 0; it < DM / 64; it++) {
            const int cur = it & 1;
            __syncthreads();
            if (it < DM / 64 - 1) STAGE_G((it + 1) * 64, cur ^ 1);
            bf16x8 af[2][2], bf[4][2];
            #pragma unroll
            for (int rt = 0; rt < 2; rt++) {
                int ra = (wr + rt*16 + lr) * 64;
                af[rt][0] = *(const bf16x8*)&As[cur][ra + kg0];
                af[rt][1] = *(const bf16x8*)&As[cur][ra + kg1];
            }
            #pragma unroll
            for (int ct = 0; ct < 4; ct++) {
                int rb = (wc + ct*16 + lr) * 64;
                bf[ct][0] = *(const bf16x8*)&Bs[cur][rb + kg0];
                bf[ct][1] = *(const bf16x8*)&Bs[cur][rb + kg1];
            }
            #pragma unroll
            for (int ks = 0; ks < 2; ks++)
                #pragma unroll
                for (int rt = 0; rt < 2; rt++)
                    #pragma unroll
                    for (int ct = 0; ct < 4; ct++)
                        acc[rt][ct] = __builtin_amdgcn_mfma_f32_16x16x32_bf16(bf[ct][ks], af[rt][ks], acc[rt][ct], 0, 0, 0);
        }
        // Swapped epilogue: D row (lq*4+i) = e within bf[ct] block; D col (lr) = t within af[rt]
        const float* bias_p = (region == 0) ? bq : bk;
        const float  scale  = (region == 0) ? QSCALE : 1.0f;
        unsigned short* dst = (region == 0) ? Q : Kg;
        #pragma unroll
        for (int ct = 0; ct < 4; ct++) {
            int r0 = n0 + wc + ct*16 + lq*4 - region*DM;
            int h = r0 >> 6, e = r0 & 63;
            float4 b4 = *(const float4*)&bias_p[r0];
            unsigned short* drow = dst + (size_t)(b*NH + h)*TT*HD + e;
            #pragma unroll
            for (int rt = 0; rt < 2; rt++) {
                int t = tb + wr + rt*16 + lr;
                ushort4 o;
                o.x = f2bf((acc[rt][ct][0] + b4.x) * scale);
                o.y = f2bf((acc[rt][ct][1] + b4.y) * scale);
                o.z = f2bf((acc[rt][ct][2] + b4.z) * scale);
                o.w = f2bf((acc[rt][ct][3] + b4.w) * scale);
                *(ushort4*)&drow[(size_t)t * HD] = o;
            }
        }
    }
    #undef STAGE_G
}

// ---------------- Flash attention v9: permlane P-redistribution (zero-LDS P) ----------------
// VERIFIED 65.0us, bank-conflict 0. K loaded with row-permutation sigma; x32 B-fragment
// via 2x v_permlane32_swap per pair set. v6/v8 lesson: MFMA operands MUST feed from LDS.
__global__ __launch_bounds__(256, 3) void k_flash(
    const unsigned short* __restrict__ Q, const unsigned short* __restrict__ Kg,
    const unsigned short* __restrict__ Vt, unsigned short* __restrict__ A2)
{
    __shared__ unsigned short Ks[2][4096];   // [buf][krow*64 + d-grp swizzled]
    __shared__ unsigned short Vs[2][4096];   // [buf][e*64 + t-grp swizzled]
    // XCD-chunked swizzle: 768 blocks % 8 == 0, chunk = 96 = 6 heads x 16 q-tiles.
    const int flat = blockIdx.y * (BB*NH) + blockIdx.x;
    const int swz  = (flat & 7) * 96 + (flat >> 3);
    const int bh = swz >> 4, qt = swz & 15;
    const int b = bh / NH, h = bh % NH;
    const int tid = threadIdx.x, lane = tid & 63, w = tid >> 6;
    const int col = lane & 15, quad = lane >> 4;
    const size_t qk_base = (size_t)bh * TT * HD;
    const size_t vt_base = (size_t)bh * HD * TT;
    const int tq0 = qt * 128 + w * 32;

    const int srow  = tid >> 3;
    const int sperm = (tid & 7) ^ (srow & 7);
    const int koff0 = srow * HD + sperm * 8;
    const int voff0 = srow * TT + sperm * 8;
    const int lds0  = w * 512;

    const unsigned short* ksrc = Kg + qk_base;
    const unsigned short* vsrc = Vt + vt_base;

    const int c7 = col & 7;
    // sigma-permuted K-row read: row = scol, XOR-swizzle keyed by scol&7
    const int scol = ((col >> 2) & 1) * 8 + ((col >> 3) & 1) * 4 + (col & 3);
    const int sc7  = scol & 7;
    const int ra0 = scol * 64 + (((    quad) ^ sc7) * 8);
    const int ra1 = scol * 64 + (((4 + quad) ^ sc7) * 8);

    bf16x8 aq[2][2];
    #pragma unroll
    for (int rt = 0; rt < 2; rt++)
        #pragma unroll
        for (int ks = 0; ks < 2; ks++)
            aq[rt][ks] = *(const bf16x8*)&Q[qk_base + (size_t)(tq0 + rt*16 + col) * HD + ks*32 + quad*8];

    const bf16x8 ones8 = { (short)0x3F80, (short)0x3F80, (short)0x3F80, (short)0x3F80,
                           (short)0x3F80, (short)0x3F80, (short)0x3F80, (short)0x3F80 };

    f32x4 co[4][2] = {};
    f32x4 lacc[2] = {};

    #define STAGE(kt_, buf_) do { \
        const unsigned short* kb_ = ksrc + (size_t)(kt_) * 64 * HD; \
        const unsigned short* vb_ = vsrc + (kt_) * 64; \
        GLDS(kb_ + koff0,           &Ks[buf_][lds0]); \
        GLDS(kb_ + koff0 + 32*HD,   &Ks[buf_][lds0 + 2048]); \
        GLDS(vb_ + voff0,           &Vs[buf_][lds0]); \
        GLDS(vb_ + voff0 + 32*TT,   &Vs[buf_][lds0 + 2048]); \
    } while (0)

    STAGE(0, 0);

    for (int kt = 0; kt < TT/64; kt++) {
        const int cur = kt & 1;
        __syncthreads();
        if (kt < TT/64 - 1) STAGE(kt + 1, cur ^ 1);

        bf16x8 kf[4][2];
        #pragma unroll
        for (int ct = 0; ct < 4; ct++) {
            kf[ct][0] = *(const bf16x8*)&Ks[cur][ct*1024 + ra0];
            kf[ct][1] = *(const bf16x8*)&Ks[cur][ct*1024 + ra1];
        }

        f32x4 cs[4][2] = {};
        __builtin_amdgcn_s_setprio(1);
        #pragma unroll
        for (int ks = 0; ks < 2; ks++)
            #pragma unroll
            for (int ct = 0; ct < 4; ct++)
                #pragma unroll
                for (int rt = 0; rt < 2; rt++)
                    cs[ct][rt] = __builtin_amdgcn_mfma_f32_16x16x32_bf16(kf[ct][ks], aq[rt][ks], cs[ct][rt], 0, 0, 0);
        __builtin_amdgcn_s_setprio(0);

        // exp2 + pack to bf16 pairs: pk[rt][ct][m] = rows ct*16+sigma(quad*4+{2m,2m+1})
        int pk[2][4][2];
        #pragma unroll
        for (int rt = 0; rt < 2; rt++) {
            #pragma unroll
            for (int ct = 0; ct < 4; ct++) {
                float p0 = __builtin_amdgcn_exp2f(cs[ct][rt][0]);
                float p1 = __builtin_amdgcn_exp2f(cs[ct][rt][1]);
                float p2 = __builtin_amdgcn_exp2f(cs[ct][rt][2]);
                float p3 = __builtin_amdgcn_exp2f(cs[ct][rt][3]);
                pk[rt][ct][0] = (int)__builtin_amdgcn_perm(__float_as_uint(p1), __float_as_uint(p0), 0x07060302u);
                pk[rt][ct][1] = (int)__builtin_amdgcn_perm(__float_as_uint(p3), __float_as_uint(p2), 0x07060302u);
            }
        }

        // permlane32_swap redistribution -> x32 B-fragments (no LDS, no barrier)
        bf16x8 pf[2][2];
        #pragma unroll
        for (int rt = 0; rt < 2; rt++)
            #pragma unroll
            for (int k4 = 0; k4 < 2; k4++) {
                i32x2 s0 = __builtin_amdgcn_permlane32_swap(pk[rt][2*k4][0], pk[rt][2*k4+1][0], false, false);
                i32x2 s1 = __builtin_amdgcn_permlane32_swap(pk[rt][2*k4][1], pk[rt][2*k4+1][1], false, false);
                i32x4 pw; pw[0] = s0[0]; pw[1] = s1[0]; pw[2] = s0[1]; pw[3] = s1[1];
                pf[rt][k4] = __builtin_bit_cast(bf16x8, pw);
            }

        __builtin_amdgcn_s_setprio(1);
        #pragma unroll
        for (int rt = 0; rt < 2; rt++)
            #pragma unroll
            for (int k4 = 0; k4 < 2; k4++)
                lacc[rt] = __builtin_amdgcn_mfma_f32_16x16x32_bf16(ones8, pf[rt][k4], lacc[rt], 0, 0, 0);
        #pragma unroll
        for (int cv = 0; cv < 4; cv++) {
            #pragma unroll
            for (int k4 = 0; k4 < 2; k4++) {
                bf16x8 vf = *(const bf16x8*)&Vs[cur][cv*1024 + col*64 + ((k4*4 + quad) ^ c7)*8];
                #pragma unroll
                for (int rt = 0; rt < 2; rt++)
                    co[cv][rt] = __builtin_amdgcn_mfma_f32_16x16x32_bf16(vf, pf[rt][k4], co[cv][rt], 0, 0, 0);
            }
        }
        __builtin_amdgcn_s_setprio(0);
    }
    #undef STAGE

    #pragma unroll
    for (int rt = 0; rt < 2; rt++) {
        float inv = 1.0f / lacc[rt][0];   // ones-MFMA summed all k; all rows equal
        int t = tq0 + rt*16 + col;
        #pragma unroll
        for (int cv = 0; cv < 4; cv++) {
            ushort4 o;
            o.x = f2bf(co[cv][rt][0] * inv);
            o.y = f2bf(co[cv][rt][1] * inv);
            o.z = f2bf(co[cv][rt][2] * inv);
            o.w = f2bf(co[cv][rt][3] * inv);
            *(ushort4*)&A2[(size_t)(b*TT + t) * DM + h*HD + cv*16 + quad*4] = o;
        }
    }
}

// ---------------- GEMM: output projection (64x128 tile, balanced 768 blocks = 3/CU) ----------------
__global__ __launch_bounds__(256) void k_gemm_out(
    const unsigned short* __restrict__ A,
    const unsigned short* __restrict__ Bt,
    const float* __restrict__ bias,
    float* __restrict__ out)
{
    __shared__ unsigned short As[2][2048];   // 64 rows x 32 k
    __shared__ unsigned short Bs[2][4096];   // 128 rows x 32 k
    // XCD-chunked swizzle: 768 blocks % 8 == 0, chunk = 96.
    const int flat = blockIdx.y * 6 + blockIdx.x;
    const int swz  = (flat & 7) * 96 + (flat >> 3);
    const int m0 = (swz / 6) * 64, n0 = (swz % 6) * 128;
    const int tid = threadIdx.x, lane = tid & 63, w = tid >> 6;
    const int wr = (w >> 1) * 32, wc = (w & 1) * 64;
    const int lr = lane & 15, lq = lane >> 4;

    const int arow = tid >> 2;
    const int ag   = ((tid & 3) ^ (arow & 3)) * 8;
    const int ldsw = w * 512;
    const int kg = (lq ^ (lr & 3)) * 8;

    #define STAGE_G(k0_, buf_) do { \
        const unsigned short* a_ = A  + (size_t)(m0 + arow) * DM + (k0_) + ag; \
        const unsigned short* b_ = Bt + (size_t)(n0 + arow) * DM + (k0_) + ag; \
        GLDS(a_,             &As[buf_][ldsw]); \
        GLDS(b_,             &Bs[buf_][ldsw]); \
        GLDS(b_ + 64 * DM,   &Bs[buf_][2048 + ldsw]); \
    } while (0)

    f32x4 acc[2][4] = {};
    STAGE_G(0, 0);
    for (int it = 0; it < DM / 32; it++) {
        const int cur = it & 1;
        __syncthreads();
        if (it < DM / 32 - 1) STAGE_G((it + 1) * 32, cur ^ 1);
        bf16x8 af[2], bf[4];
        #pragma unroll
        for (int rt = 0; rt < 2; rt++) af[rt] = *(const bf16x8*)&As[cur][(wr + rt*16 + lr) * 32 + kg];
        #pragma unroll
        for (int ct = 0; ct < 4; ct++) bf[ct] = *(const bf16x8*)&Bs[cur][(wc + ct*16 + lr) * 32 + kg];
        #pragma unroll
        for (int rt = 0; rt < 2; rt++)
            #pragma unroll
            for (int ct = 0; ct < 4; ct++)
                acc[rt][ct] = __builtin_amdgcn_mfma_f32_16x16x32_bf16(bf[ct], af[rt], acc[rt][ct], 0, 0, 0);
    }
    #undef STAGE_G

    #pragma unroll
    for (int ct = 0; ct < 4; ct++) {
        int n = n0 + wc + ct*16 + lq*4;
        float4 b4 = *(const float4*)&bias[n];
        #pragma unroll
        for (int rt = 0; rt < 2; rt++) {
            int m = m0 + wr + rt*16 + lr;
            float4 o = { acc[rt][ct][0] + b4.x, acc[rt][ct][1] + b4.y,
                         acc[rt][ct][2] + b4.z, acc[rt][ct][3] + b4.w };
            *(float4*)&out[(size_t)m * DM + n] = o;
        }
    }
}

// ---------------- launcher ----------------
extern "C" void kernel_launch(void* const* d_in, const int* in_sizes, int n_in,
                              void* d_out, int out_size, void* d_ws, size_t ws_size,
                              hipStream_t stream) {
    const float* x    = (const float*)d_in[0];
    const float* Wq   = (const float*)d_in[1];
    const float* bq   = (const float*)d_in[2];
    const float* Wk   = (const float*)d_in[3];
    const float* bk   = (const float*)d_in[4];
    const float* Wv   = (const float*)d_in[5];
    const float* bv   = (const float*)d_in[6];
    const float* Wo   = (const float*)d_in[7];
    const float* bo   = (const float*)d_in[8];
    const float* gate = (const float*)d_in[9];
    float* out = (float*)d_out;

    char* p = (char*)d_ws;
    unsigned short* Xb   = (unsigned short*)p;  p += (size_t)MTOT*DM*2;
    unsigned short* Wqkv = (unsigned short*)p;  p += (size_t)3*DM*DM*2;
    unsigned short* Qb   = (unsigned short*)p;  p += (size_t)BB*NH*TT*HD*2;
    unsigned short* Kb   = (unsigned short*)p;  p += (size_t)BB*NH*TT*HD*2;
    unsigned short* Vtb  = (unsigned short*)p;  p += (size_t)BB*NH*TT*HD*2;
    unsigned short* A2   = (unsigned short*)p;  p += (size_t)MTOT*DM*2;
    unsigned short* Wob  = (unsigned short*)p;  p += (size_t)DM*DM*2;
    float*          bio  = (float*)p;           p += (size_t)DM*4;

    k_pack_all <<<PACKX_BLOCKS + 432 + 145, 256, 0, stream>>>(x, Xb, Wq, Wk, Wv, Wqkv, Wo, gate, Wob, bo, bio);
    k_gemm_qkv <<<dim3(18, MTOT/64), 256, 0, stream>>>(Xb, Wqkv, bq, bk, bv, Qb, Kb, Vtb);
    k_flash    <<<dim3(BB*NH, TT/128), 256, 0, stream>>>(Qb, Kb, Vtb, A2);
    k_gemm_out <<<dim3(DM/128, MTOT/64), 256, 0, stream>>>(A2, Wob, bio, out);
}